// Round 11
// baseline (302.653 us; speedup 1.0000x reference)
//
#include <hip/hip_runtime.h>
#include <math.h>

#define NN 50000
#define NE 800000
#define HH 4
#define DD 32

typedef __attribute__((ext_vector_type(8))) short short8;
typedef __attribute__((ext_vector_type(4))) float f32x4;

__device__ __forceinline__ unsigned short f2bf(float x) {
    unsigned u = __float_as_uint(x);
    unsigned r = (u + 0x7FFF + ((u >> 16) & 1)) >> 16;  // RNE
    return (unsigned short)r;
}

__device__ __forceinline__ short8 pack8(float4 p, float4 q) {
    short8 r;
    r[0] = (short)f2bf(p.x); r[1] = (short)f2bf(p.y);
    r[2] = (short)f2bf(p.z); r[3] = (short)f2bf(p.w);
    r[4] = (short)f2bf(q.x); r[5] = (short)f2bf(q.y);
    r[6] = (short)f2bf(q.z); r[7] = (short)f2bf(q.w);
    return r;
}

// bf16-pair unpack from one 32-bit word (lo = even channel, hi = odd)
__device__ __forceinline__ float bflo(unsigned u) { return __uint_as_float(u << 16); }
__device__ __forceinline__ float bfhi(unsigned u) { return __uint_as_float(u & 0xFFFF0000u); }

// ---------------- MFMA GEMM: ft[n,o] = bf16(sum_k feat[n,k] * W[o,k]) ----------------
__global__ __launch_bounds__(256) void k_gemm(const float* __restrict__ feat,
                                              const float* __restrict__ W,
                                              unsigned short* __restrict__ ft, int N) {
    __shared__ short8 wlds[2048];  // [kc][ct][lane] -> 16B frag; 32 KB

    int tid = threadIdx.x;
#pragma unroll
    for (int j = 0; j < 8; ++j) {
        int f = tid + j * 256;
        int kc = f >> 9, ct = (f >> 6) & 7, l = f & 63;
        int o = ct * 16 + (l & 15);
        int kb = kc * 32 + ((l >> 4) << 3);
        const float* wp = W + o * 128 + kb;
        float4 p = *(const float4*)wp;
        float4 q = *(const float4*)(wp + 4);
        wlds[f] = pack8(p, q);
    }
    __syncthreads();

    int l = tid & 63;
    int w = tid >> 6;
    int row0 = blockIdx.x * 64;
    int arow = row0 + w * 16 + (l & 15);
    bool valid = arow < N;
    const float* fb = feat + (size_t)(valid ? arow : 0) * 128 + ((l >> 4) << 3);

    f32x4 acc[8];
#pragma unroll
    for (int ct = 0; ct < 8; ++ct) acc[ct] = (f32x4){0.f, 0.f, 0.f, 0.f};

#pragma unroll
    for (int kc = 0; kc < 4; ++kc) {
        short8 a;
        if (valid) {
            float4 p = *(const float4*)(fb + kc * 32);
            float4 q = *(const float4*)(fb + kc * 32 + 4);
            a = pack8(p, q);
        } else {
            a = (short8){0, 0, 0, 0, 0, 0, 0, 0};
        }
#pragma unroll
        for (int ct = 0; ct < 8; ++ct) {
            short8 b = wlds[kc * 512 + ct * 64 + l];
            acc[ct] = __builtin_amdgcn_mfma_f32_16x16x32_bf16(a, b, acc[ct], 0, 0, 0);
        }
    }

    int oc = l & 15;
    int rg = l >> 4;
#pragma unroll
    for (int i = 0; i < 4; ++i) {
        int r = row0 + w * 16 + rg * 4 + i;
        if (r < N) {
            unsigned short* op = ft + (size_t)r * 128 + oc;
#pragma unroll
            for (int ct = 0; ct < 8; ++ct) op[ct * 16] = f2bf(acc[ct][i]);
        }
    }
}

// ---------------- CSR build: rank (hist+rank in one atomic pass) ----------------
__global__ __launch_bounds__(256) void k_rank(const int* __restrict__ dst,
                                              int* __restrict__ cnt,
                                              int* __restrict__ pos) {
    int e = blockIdx.x * 256 + threadIdx.x;
    if (e < NE) pos[e] = atomicAdd(&cnt[dst[e]], 1);
}

// single-block exclusive scan of cnt[NN] -> row[NN+1] (1024 thr, ~49 elems each)
__global__ __launch_bounds__(1024) void k_scan(const int* __restrict__ cnt,
                                               int* __restrict__ row) {
    __shared__ int sh[1024];
    const int C = (NN + 1023) / 1024;  // 49
    int t = threadIdx.x;
    int i0 = t * C;
    int sum = 0;
    for (int j = 0; j < C; ++j) {
        int i = i0 + j;
        if (i < NN) sum += cnt[i];
    }
    sh[t] = sum;
    __syncthreads();
    for (int off = 1; off < 1024; off <<= 1) {
        int v = (t >= off) ? sh[t - off] : 0;
        __syncthreads();
        sh[t] += v;
        __syncthreads();
    }
    int pre = sh[t] - sum;  // exclusive prefix of this thread's chunk
    for (int j = 0; j < C; ++j) {
        int i = i0 + j;
        if (i < NN) {
            int c = cnt[i];
            row[i] = pre;
            pre += c;
        }
    }
    if (t == 0) row[NN] = NE;
}

__global__ __launch_bounds__(256) void k_fill(const int* __restrict__ src, const int* __restrict__ dst,
                                              const int* __restrict__ row, const int* __restrict__ pos,
                                              int* __restrict__ srcs) {
    int e = blockIdx.x * 256 + threadIdx.x;
    if (e >= NE) return;
    srcs[row[dst[e]] + pos[e]] = src[e];  // no atomics
}

// ---------------- fused edge-dot + online softmax + aggregate (bf16 gathers) ----------------
// one WAVE per dst node; lane l owns channels 2l,2l+1 packed in one u32.
__global__ __launch_bounds__(256) void k_agg(const unsigned* __restrict__ ftb,
                                             const int* __restrict__ row,
                                             const int* __restrict__ srcs,
                                             float2* __restrict__ out2) {
    int n = blockIdx.x * 4 + (threadIdx.x >> 6);
    int l = threadIdx.x & 63;
    int r0 = row[n], r1 = row[n + 1];
    size_t base = (size_t)n * 64 + l;
    unsigned ud = ftb[base];
    float fdx = bflo(ud), fdy = bfhi(ud);  // dst row, loaded once
    float m = -INFINITY, s = 0.f;
    float ax = 0.f, ay = 0.f;
    int p = r0;
    for (; p + 1 < r1; p += 2) {
        int s0 = srcs[p], s1 = srcs[p + 1];
        unsigned u0 = ftb[(size_t)s0 * 64 + l];
        unsigned u1 = ftb[(size_t)s1 * 64 + l];
        float f0x = bflo(u0), f0y = bfhi(u0);
        float f1x = bflo(u1), f1y = bfhi(u1);
        float v0 = fdx * f0x + fdy * f0y;
        float v1 = fdx * f1x + fdy * f1y;
        v0 += __shfl_xor(v0, 1);  v1 += __shfl_xor(v1, 1);
        v0 += __shfl_xor(v0, 2);  v1 += __shfl_xor(v1, 2);
        v0 += __shfl_xor(v0, 4);  v1 += __shfl_xor(v1, 4);
        v0 += __shfl_xor(v0, 8);  v1 += __shfl_xor(v1, 8);
        v0 *= 0.17677669529663687f;  // 1/sqrt(32)
        v1 *= 0.17677669529663687f;
        float mn = fmaxf(fmaxf(m, v0), v1);  // v_max3
        float sc = __expf(m - mn);           // 0 on first pair (m=-inf)
        float w0 = __expf(v0 - mn);
        float w1 = __expf(v1 - mn);
        s = s * sc + w0 + w1;
        ax = ax * sc + w0 * f0x + w1 * f1x;
        ay = ay * sc + w0 * f0y + w1 * f1y;
        m = mn;
    }
    if (p < r1) {  // odd tail
        int s0 = srcs[p];
        unsigned u0 = ftb[(size_t)s0 * 64 + l];
        float f0x = bflo(u0), f0y = bfhi(u0);
        float v0 = fdx * f0x + fdy * f0y;
        v0 += __shfl_xor(v0, 1);
        v0 += __shfl_xor(v0, 2);
        v0 += __shfl_xor(v0, 4);
        v0 += __shfl_xor(v0, 8);
        v0 *= 0.17677669529663687f;
        float mn = fmaxf(m, v0);
        float sc = __expf(m - mn);
        float w0 = __expf(v0 - mn);
        s = s * sc + w0;
        ax = ax * sc + w0 * f0x;
        ay = ay * sc + w0 * f0y;
    }
    float inv = (r1 > r0) ? 1.f / s : 0.f;
    out2[base] = make_float2(ax * inv, ay * inv);
}

extern "C" void kernel_launch(void* const* d_in, const int* in_sizes, int n_in,
                              void* d_out, int out_size, void* d_ws, size_t ws_size,
                              hipStream_t stream) {
    const float* feat = (const float*)d_in[0];
    const float* W    = (const float*)d_in[1];
    const int*   src  = (const int*)d_in[2];
    const int*   dst  = (const int*)d_in[3];
    float* out = (float*)d_out;

    // workspace layout
    unsigned short* ft = (unsigned short*)d_ws;             // 6.4M bf16 = 12.8 MB
    int* row  = (int*)(ft + (size_t)NN * 128);              // 50,001
    int* pos  = row + (NN + 1);                             // 800,000
    int* srcs = pos + NE;                                   // 800,000
    int* cnt  = srcs + NE;                                  // 50,000

    hipMemsetAsync(cnt, 0, (size_t)NN * sizeof(int), stream);
    k_gemm<<<(NN + 63) / 64, 256, 0, stream>>>(feat, W, ft, NN);
    k_rank<<<(NE + 255) / 256, 256, 0, stream>>>(dst, cnt, pos);
    k_scan<<<1, 1024, 0, stream>>>(cnt, row);
    k_fill<<<(NE + 255) / 256, 256, 0, stream>>>(src, dst, row, pos, srcs);
    k_agg<<<NN / 4, 256, 0, stream>>>((const unsigned*)ft, row, srcs, (float2*)out);
}

// Round 12
// 210.547 us; speedup vs baseline: 1.4375x; 1.4375x over previous
//
#include <hip/hip_runtime.h>
#include <math.h>

#define NN 50000
#define NE 800000
#define HH 4
#define DD 32

typedef __attribute__((ext_vector_type(8))) short short8;
typedef __attribute__((ext_vector_type(4))) float f32x4;

__device__ __forceinline__ unsigned short f2bf(float x) {
    unsigned u = __float_as_uint(x);
    unsigned r = (u + 0x7FFF + ((u >> 16) & 1)) >> 16;  // RNE
    return (unsigned short)r;
}

__device__ __forceinline__ short8 pack8(float4 p, float4 q) {
    short8 r;
    r[0] = (short)f2bf(p.x); r[1] = (short)f2bf(p.y);
    r[2] = (short)f2bf(p.z); r[3] = (short)f2bf(p.w);
    r[4] = (short)f2bf(q.x); r[5] = (short)f2bf(q.y);
    r[6] = (short)f2bf(q.z); r[7] = (short)f2bf(q.w);
    return r;
}

// bf16-pair unpack from one 32-bit word (lo = even channel, hi = odd)
__device__ __forceinline__ float bflo(unsigned u) { return __uint_as_float(u << 16); }
__device__ __forceinline__ float bfhi(unsigned u) { return __uint_as_float(u & 0xFFFF0000u); }

// ---------------- MFMA GEMM: ft[n,o] = bf16(sum_k feat[n,k] * W[o,k]) ----------------
__global__ __launch_bounds__(256) void k_gemm(const float* __restrict__ feat,
                                              const float* __restrict__ W,
                                              unsigned short* __restrict__ ft, int N) {
    __shared__ short8 wlds[2048];  // [kc][ct][lane] -> 16B frag; 32 KB

    int tid = threadIdx.x;
#pragma unroll
    for (int j = 0; j < 8; ++j) {
        int f = tid + j * 256;
        int kc = f >> 9, ct = (f >> 6) & 7, l = f & 63;
        int o = ct * 16 + (l & 15);
        int kb = kc * 32 + ((l >> 4) << 3);
        const float* wp = W + o * 128 + kb;
        float4 p = *(const float4*)wp;
        float4 q = *(const float4*)(wp + 4);
        wlds[f] = pack8(p, q);
    }
    __syncthreads();

    int l = tid & 63;
    int w = tid >> 6;
    int row0 = blockIdx.x * 64;
    int arow = row0 + w * 16 + (l & 15);
    bool valid = arow < N;
    const float* fb = feat + (size_t)(valid ? arow : 0) * 128 + ((l >> 4) << 3);

    f32x4 acc[8];
#pragma unroll
    for (int ct = 0; ct < 8; ++ct) acc[ct] = (f32x4){0.f, 0.f, 0.f, 0.f};

#pragma unroll
    for (int kc = 0; kc < 4; ++kc) {
        short8 a;
        if (valid) {
            float4 p = *(const float4*)(fb + kc * 32);
            float4 q = *(const float4*)(fb + kc * 32 + 4);
            a = pack8(p, q);
        } else {
            a = (short8){0, 0, 0, 0, 0, 0, 0, 0};
        }
#pragma unroll
        for (int ct = 0; ct < 8; ++ct) {
            short8 b = wlds[kc * 512 + ct * 64 + l];
            acc[ct] = __builtin_amdgcn_mfma_f32_16x16x32_bf16(a, b, acc[ct], 0, 0, 0);
        }
    }

    int oc = l & 15;
    int rg = l >> 4;
#pragma unroll
    for (int i = 0; i < 4; ++i) {
        int r = row0 + w * 16 + rg * 4 + i;
        if (r < N) {
            unsigned short* op = ft + (size_t)r * 128 + oc;
#pragma unroll
            for (int ct = 0; ct < 8; ++ct) op[ct * 16] = f2bf(acc[ct][i]);
        }
    }
}

// ---------------- CSR build: rank (hist+rank in one atomic pass) ----------------
__global__ __launch_bounds__(256) void k_rank(const int* __restrict__ dst,
                                              int* __restrict__ cnt,
                                              int* __restrict__ pos) {
    int e = blockIdx.x * 256 + threadIdx.x;
    if (e < NE) pos[e] = atomicAdd(&cnt[dst[e]], 1);
}

// ---------------- hierarchical scan (multi-block; latency-safe) ----------------
__global__ __launch_bounds__(256) void k_scan1(const int* __restrict__ cnt, int* __restrict__ row,
                                               int* __restrict__ partial, int n) {
    __shared__ int sh[256];
    int i = blockIdx.x * 256 + threadIdx.x;
    int x = (i < n) ? cnt[i] : 0;
    sh[threadIdx.x] = x;
    __syncthreads();
    for (int off = 1; off < 256; off <<= 1) {
        int v = (threadIdx.x >= off) ? sh[threadIdx.x - off] : 0;
        __syncthreads();
        sh[threadIdx.x] += v;
        __syncthreads();
    }
    if (i < n) row[i] = sh[threadIdx.x] - x;  // exclusive
    if (threadIdx.x == 255) partial[blockIdx.x] = sh[255];
}

__global__ __launch_bounds__(256) void k_scan2(int* __restrict__ partial, int nb) {
    __shared__ int sh[256];
    int t = threadIdx.x;
    int x = (t < nb) ? partial[t] : 0;
    sh[t] = x;
    __syncthreads();
    for (int off = 1; off < 256; off <<= 1) {
        int v = (t >= off) ? sh[t - off] : 0;
        __syncthreads();
        sh[t] += v;
        __syncthreads();
    }
    if (t < nb) partial[t] = sh[t] - x;  // exclusive block offsets
}

__global__ __launch_bounds__(256) void k_scan3(int* __restrict__ row,
                                               const int* __restrict__ partial, int n) {
    int i = blockIdx.x * 256 + threadIdx.x;
    if (i < n) row[i] += partial[blockIdx.x];
    if (i == 0) row[n] = NE;
}

__global__ __launch_bounds__(256) void k_fill(const int* __restrict__ src, const int* __restrict__ dst,
                                              const int* __restrict__ row, const int* __restrict__ pos,
                                              int* __restrict__ srcs) {
    int e = blockIdx.x * 256 + threadIdx.x;
    if (e >= NE) return;
    srcs[row[dst[e]] + pos[e]] = src[e];  // no atomics
}

// ---------------- fused edge-dot + online softmax + aggregate (bf16 gathers) ----------------
// one WAVE per dst node; lane l owns channels 2l,2l+1 packed in one u32.
__global__ __launch_bounds__(256) void k_agg(const unsigned* __restrict__ ftb,
                                             const int* __restrict__ row,
                                             const int* __restrict__ srcs,
                                             float2* __restrict__ out2) {
    int n = blockIdx.x * 4 + (threadIdx.x >> 6);
    int l = threadIdx.x & 63;
    int r0 = row[n], r1 = row[n + 1];
    size_t base = (size_t)n * 64 + l;
    unsigned ud = ftb[base];
    float fdx = bflo(ud), fdy = bfhi(ud);  // dst row, loaded once
    float m = -INFINITY, s = 0.f;
    float ax = 0.f, ay = 0.f;
    int p = r0;
    for (; p + 1 < r1; p += 2) {
        int s0 = srcs[p], s1 = srcs[p + 1];
        unsigned u0 = ftb[(size_t)s0 * 64 + l];
        unsigned u1 = ftb[(size_t)s1 * 64 + l];
        float f0x = bflo(u0), f0y = bfhi(u0);
        float f1x = bflo(u1), f1y = bfhi(u1);
        float v0 = fdx * f0x + fdy * f0y;
        float v1 = fdx * f1x + fdy * f1y;
        v0 += __shfl_xor(v0, 1);  v1 += __shfl_xor(v1, 1);
        v0 += __shfl_xor(v0, 2);  v1 += __shfl_xor(v1, 2);
        v0 += __shfl_xor(v0, 4);  v1 += __shfl_xor(v1, 4);
        v0 += __shfl_xor(v0, 8);  v1 += __shfl_xor(v1, 8);
        v0 *= 0.17677669529663687f;  // 1/sqrt(32)
        v1 *= 0.17677669529663687f;
        float mn = fmaxf(fmaxf(m, v0), v1);  // v_max3
        float sc = __expf(m - mn);           // 0 on first pair (m=-inf)
        float w0 = __expf(v0 - mn);
        float w1 = __expf(v1 - mn);
        s = s * sc + w0 + w1;
        ax = ax * sc + w0 * f0x + w1 * f1x;
        ay = ay * sc + w0 * f0y + w1 * f1y;
        m = mn;
    }
    if (p < r1) {  // odd tail
        int s0 = srcs[p];
        unsigned u0 = ftb[(size_t)s0 * 64 + l];
        float f0x = bflo(u0), f0y = bfhi(u0);
        float v0 = fdx * f0x + fdy * f0y;
        v0 += __shfl_xor(v0, 1);
        v0 += __shfl_xor(v0, 2);
        v0 += __shfl_xor(v0, 4);
        v0 += __shfl_xor(v0, 8);
        v0 *= 0.17677669529663687f;
        float mn = fmaxf(m, v0);
        float sc = __expf(m - mn);
        float w0 = __expf(v0 - mn);
        s = s * sc + w0;
        ax = ax * sc + w0 * f0x;
        ay = ay * sc + w0 * f0y;
    }
    float inv = (r1 > r0) ? 1.f / s : 0.f;
    out2[base] = make_float2(ax * inv, ay * inv);
}

extern "C" void kernel_launch(void* const* d_in, const int* in_sizes, int n_in,
                              void* d_out, int out_size, void* d_ws, size_t ws_size,
                              hipStream_t stream) {
    const float* feat = (const float*)d_in[0];
    const float* W    = (const float*)d_in[1];
    const int*   src  = (const int*)d_in[2];
    const int*   dst  = (const int*)d_in[3];
    float* out = (float*)d_out;

    // workspace layout
    unsigned short* ft = (unsigned short*)d_ws;             // 6.4M bf16 = 12.8 MB
    int* row  = (int*)(ft + (size_t)NN * 128);              // 50,001
    int* pos  = row + (NN + 1);                             // 800,000
    int* srcs = pos + NE;                                   // 800,000
    int* cnt  = srcs + NE;                                  // 50,000
    int* part = cnt + NN;                                   // 256

    const int NB1 = (NN + 255) / 256;  // 196

    hipMemsetAsync(cnt, 0, (size_t)NN * sizeof(int), stream);
    k_gemm<<<(NN + 63) / 64, 256, 0, stream>>>(feat, W, ft, NN);
    k_rank<<<(NE + 255) / 256, 256, 0, stream>>>(dst, cnt, pos);
    k_scan1<<<NB1, 256, 0, stream>>>(cnt, row, part, NN);
    k_scan2<<<1, 256, 0, stream>>>(part, NB1);
    k_scan3<<<NB1, 256, 0, stream>>>(row, part, NN);
    k_fill<<<(NE + 255) / 256, 256, 0, stream>>>(src, dst, row, pos, srcs);
    k_agg<<<NN / 4, 256, 0, stream>>>((const unsigned*)ft, row, srcs, (float2*)out);
}